// Round 13
// baseline (212.456 us; speedup 1.0000x reference)
//
#include <hip/hip_runtime.h>

// GCN layer: segment_sum(x@W^T)[dst] == segment_sum(x)[dst] @ W^T (linearity).
// Round-13: r12 pipeline with BN 128->64 (nb~1563) to double sort_gather
// residency (19.5% occ -> ~40%) and improve tail balance.
//   K1 convert_hist : 1024 thr; x->bf16 (+zero row N); LDS hist ->
//                     scanbuf[b*PB + bid]
//   K2a rowscan     : one wave per 256-entry row: in-place exclusive scan
//   K2b basescan    : one 512-thr block: exclusive scan of rowtots -> gbase
//   K3 scatter      : 1024 thr; curs[b]=gbase[b]+scanbuf[b][bid]; LDS
//                     cursors; binned[p] = (src<<6)|(dst&63)
//   K4 sort_gather  : block per 64-node bucket (~7KB LDS); LDS counting sort
//                     of its own 4KB segment; branchless quad gather (bf16
//                     dwordx4, zero-row redirect, shfl_xor reduce,
//                     readlane @ W^T epilogue)
// Tier D fallback (tiny ws / huge N): atomic scatter + LDS linear.

#define DIM 64
#define BN 64             // nodes per bucket
#define BN_SHIFT 6
#define BN_MASK 63
#define NB_MAX 2048       // max buckets in LDS (8 KB)
#define PB 256            // hist/scatter blocks (matrix width)
#define CAP 1536          // LDS src capacity per gather block (avg ~1024)

__device__ __forceinline__ unsigned short f32_to_bf16_rne(float f) {
    unsigned u = __float_as_uint(f);
    unsigned r = u + 0x7FFFu + ((u >> 16) & 1u);
    return (unsigned short)(r >> 16);
}

// ---------------------------------------------------------------------------
// K1: convert x -> bf16 (incl. zero row N) + per-block LDS histogram.
__global__ __launch_bounds__(1024) void convert_hist_kernel(
        const float* __restrict__ x, const int* __restrict__ ei,
        ushort4* __restrict__ xb4, int* __restrict__ scanbuf,
        int E, int N, int nb, int total4) {
    __shared__ int h[NB_MAX];
    const int t = threadIdx.x;
    const int bid = blockIdx.x;

    for (int b = t; b < nb; b += 1024) h[b] = 0;
    __syncthreads();

    for (int i = bid * 1024 + t; i < total4; i += PB * 1024) {
        float4 v = ((const float4*)x)[i];
        ushort4 o;
        o.x = f32_to_bf16_rne(v.x); o.y = f32_to_bf16_rne(v.y);
        o.z = f32_to_bf16_rne(v.z); o.w = f32_to_bf16_rne(v.w);
        xb4[i] = o;
    }
    if (bid == 0 && t < 16) {                 // zero row N
        ushort4 z; z.x = 0; z.y = 0; z.z = 0; z.w = 0;
        xb4[(size_t)N * 16 + t] = z;
    }

    for (int e = bid * 1024 + t; e < E; e += PB * 1024)
        atomicAdd(&h[ei[E + e] >> BN_SHIFT], 1);
    __syncthreads();
    for (int b = t; b < nb; b += 1024)
        scanbuf[b * PB + bid] = h[b];
}

// ---------------------------------------------------------------------------
// K2a: one wave per row; in-place exclusive scan of 256-entry row + rowtot.
__global__ __launch_bounds__(256) void rowscan_kernel(
        int* __restrict__ buf, int* __restrict__ rowtot, int nb) {
    const int lane = threadIdx.x & 63;
    const int row = blockIdx.x * 4 + (threadIdx.x >> 6);
    if (row >= nb) return;

    int4* r = (int4*)(buf + (size_t)row * PB);
    int4 v = r[lane];
    int s0 = v.x, s1 = s0 + v.y, s2 = s1 + v.z, s3 = s2 + v.w;
    int ls = s3;
    int incl = ls;
    #pragma unroll
    for (int d = 1; d < 64; d <<= 1) {
        int u = __shfl_up(incl, d, 64);
        if (lane >= d) incl += u;
    }
    int excl = incl - ls;
    int4 w;
    w.x = excl; w.y = excl + s0; w.z = excl + s1; w.w = excl + s2;
    r[lane] = w;
    if (lane == 63) rowtot[row] = incl;
}

// ---------------------------------------------------------------------------
// K2b: single block (512 thr) scans nb rowtots -> gbase[nb+1].
__global__ __launch_bounds__(512) void basescan_kernel(
        const int* __restrict__ rowtot, int* __restrict__ gbase, int nb, int E) {
    __shared__ int tot[NB_MAX];
    __shared__ int tmp[512];
    const int t = threadIdx.x;
    for (int j = t; j < NB_MAX; j += 512) tot[j] = (j < nb) ? rowtot[j] : 0;
    __syncthreads();
    int c0 = tot[4 * t + 0], c1 = tot[4 * t + 1];
    int c2 = tot[4 * t + 2], c3 = tot[4 * t + 3];
    int s4 = c0 + c1 + c2 + c3;
    tmp[t] = s4;
    __syncthreads();
    #pragma unroll
    for (int d = 1; d < 512; d <<= 1) {
        int u = (t >= d) ? tmp[t - d] : 0;
        __syncthreads();
        tmp[t] += u;
        __syncthreads();
    }
    int excl = tmp[t] - s4;
    if (4 * t + 0 < nb) gbase[4 * t + 0] = excl;
    if (4 * t + 1 < nb) gbase[4 * t + 1] = excl + c0;
    if (4 * t + 2 < nb) gbase[4 * t + 2] = excl + c0 + c1;
    if (4 * t + 3 < nb) gbase[4 * t + 3] = excl + c0 + c1 + c2;
    if (t == 0) gbase[nb] = E;
}

// ---------------------------------------------------------------------------
// K3: scatter edges into bucket-grouped binned[] via LDS cursors.
__global__ __launch_bounds__(1024) void scatter_kernel(
        const int* __restrict__ ei, const int* __restrict__ scanbuf,
        const int* __restrict__ gbase, int* __restrict__ binned, int E, int nb) {
    __shared__ int curs[NB_MAX];
    const int t = threadIdx.x;
    const int bid = blockIdx.x;

    for (int b = t; b < nb; b += 1024)
        curs[b] = gbase[b] + scanbuf[b * PB + bid];
    __syncthreads();

    for (int e = bid * 1024 + t; e < E; e += PB * 1024) {
        int s = ei[e];
        int d = ei[E + e];
        int p = atomicAdd(&curs[d >> BN_SHIFT], 1);
        binned[p] = (s << BN_SHIFT) | (d & BN_MASK);
    }
}

// ---------------------------------------------------------------------------
// Gather helpers (proven r8/r10/r11).
__device__ __forceinline__ void acc8(float (&a)[8], const uint4& v) {
    a[0] += __uint_as_float(v.x << 16); a[1] += __uint_as_float(v.x & 0xFFFF0000u);
    a[2] += __uint_as_float(v.y << 16); a[3] += __uint_as_float(v.y & 0xFFFF0000u);
    a[4] += __uint_as_float(v.z << 16); a[5] += __uint_as_float(v.z & 0xFFFF0000u);
    a[6] += __uint_as_float(v.w << 16); a[7] += __uint_as_float(v.w & 0xFFFF0000u);
}

__device__ __forceinline__ float epilogue64(const float (&a)[8],
                                            const float (&wv)[DIM], float bb) {
    float r0 = bb, r1 = 0.f, r2 = 0.f, r3 = 0.f;
    #pragma unroll
    for (int k = 0; k < DIM; k += 4) {
        r0 += __int_as_float(__builtin_amdgcn_readlane(
                  __float_as_int(a[(k + 0) & 7]), (k + 0) >> 3)) * wv[k + 0];
        r1 += __int_as_float(__builtin_amdgcn_readlane(
                  __float_as_int(a[(k + 1) & 7]), (k + 1) >> 3)) * wv[k + 1];
        r2 += __int_as_float(__builtin_amdgcn_readlane(
                  __float_as_int(a[(k + 2) & 7]), (k + 2) >> 3)) * wv[k + 2];
        r3 += __int_as_float(__builtin_amdgcn_readlane(
                  __float_as_int(a[(k + 3) & 7]), (k + 3) >> 3)) * wv[k + 3];
    }
    return (r0 + r1) + (r2 + r3);
}

// ---------------------------------------------------------------------------
// K4: block per 64-node bucket. LDS counting sort of its own ~4KB segment,
// then branchless quad gather.
__global__ __launch_bounds__(256) void sort_gather_kernel(
        const unsigned short* __restrict__ xh, const int* __restrict__ binned,
        const int* __restrict__ gbase, int* __restrict__ gsrcs,
        const float* __restrict__ W, const float* __restrict__ bias,
        float* __restrict__ out, int N, int E) {
    __shared__ int cnt[BN];
    __shared__ int basel[BN + 1];
    __shared__ int tmp[BN];
    __shared__ int slds[CAP];

    const int t = threadIdx.x;
    const int g = blockIdx.x;
    const int lane = t & 63;
    const int wid = t >> 6;
    const int node0 = g << BN_SHIFT;

    float wv[DIM];
    #pragma unroll
    for (int k4 = 0; k4 < DIM / 4; ++k4) {
        float4 tw = *(const float4*)(W + (size_t)lane * DIM + k4 * 4);
        wv[k4 * 4 + 0] = tw.x; wv[k4 * 4 + 1] = tw.y;
        wv[k4 * 4 + 2] = tw.z; wv[k4 * 4 + 3] = tw.w;
    }
    const float bb = bias[lane];

    const int seg0 = gbase[g];
    const int seg1 = gbase[g + 1];
    const int total = seg1 - seg0;

    if (t < BN) cnt[t] = 0;
    __syncthreads();

    for (int i = seg0 + t; i < seg1; i += 256)
        atomicAdd(&cnt[binned[i] & BN_MASK], 1);
    __syncthreads();

    int myv = (t < BN) ? cnt[t] : 0;
    if (t < BN) tmp[t] = myv;
    __syncthreads();
    #pragma unroll
    for (int d = 1; d < BN; d <<= 1) {
        int u = (t < BN && t >= d) ? tmp[t - d] : 0;
        __syncthreads();
        if (t < BN) tmp[t] += u;
        __syncthreads();
    }
    if (t < BN) basel[t] = tmp[t] - myv;
    if (t == BN - 1) basel[BN] = tmp[t];
    if (t < BN) cnt[t] = tmp[t] - myv;        // cursors
    __syncthreads();

    const bool fits = (total <= CAP);
    if (fits) {
        for (int i = seg0 + t; i < seg1; i += 256) {
            int v = binned[i];                // L2-hot re-read (4KB window)
            int p = atomicAdd(&cnt[v & BN_MASK], 1);
            slds[p] = v >> BN_SHIFT;
        }
    } else {
        for (int i = seg0 + t; i < seg1; i += 256) {
            int v = binned[i];
            int p = atomicAdd(&cnt[v & BN_MASK], 1);
            gsrcs[seg0 + p] = v >> BN_SHIFT;
        }
    }
    __syncthreads();

    const int sub8 = lane >> 3;
    const int fb   = (lane & 7) << 3;
    const int zrow = N;
    const int slast = E + 48;
    for (int q = wid; q < (BN >> 2); q += 4) {
        const int nl = q << 2;
        int b0 = basel[nl + 0], e0 = basel[nl + 1];
        int b1 = basel[nl + 1], e1 = basel[nl + 2];
        int b2 = basel[nl + 2], e2 = basel[nl + 3];
        int b3 = basel[nl + 3], e3 = basel[nl + 4];
        int c0 = (e0 - b0 + 7) >> 3, c1 = (e1 - b1 + 7) >> 3;
        int c2 = (e2 - b2 + 7) >> 3, c3 = (e3 - b3 + 7) >> 3;
        int cmax = max(max(c0, c1), max(c2, c3));
        cmax = __builtin_amdgcn_readfirstlane(cmax);

        float A0[8] = {0.f,0.f,0.f,0.f,0.f,0.f,0.f,0.f};
        float A1[8] = {0.f,0.f,0.f,0.f,0.f,0.f,0.f,0.f};
        float A2[8] = {0.f,0.f,0.f,0.f,0.f,0.f,0.f,0.f};
        float A3[8] = {0.f,0.f,0.f,0.f,0.f,0.f,0.f,0.f};

        if (fits) {
            for (int c = 0; c < cmax; ++c) {
                const int o = (c << 3) + sub8;
                int i0 = b0 + o, i1 = b1 + o, i2 = b2 + o, i3 = b3 + o;
                int s0 = slds[min(i0, CAP - 1)];
                int s1 = slds[min(i1, CAP - 1)];
                int s2 = slds[min(i2, CAP - 1)];
                int s3 = slds[min(i3, CAP - 1)];
                s0 = (i0 < e0) ? s0 : zrow;
                s1 = (i1 < e1) ? s1 : zrow;
                s2 = (i2 < e2) ? s2 : zrow;
                s3 = (i3 < e3) ? s3 : zrow;
                uint4 v0 = *(const uint4*)(xh + (size_t)s0 * DIM + fb);
                uint4 v1 = *(const uint4*)(xh + (size_t)s1 * DIM + fb);
                uint4 v2 = *(const uint4*)(xh + (size_t)s2 * DIM + fb);
                uint4 v3 = *(const uint4*)(xh + (size_t)s3 * DIM + fb);
                acc8(A0, v0); acc8(A1, v1); acc8(A2, v2); acc8(A3, v3);
            }
        } else {
            for (int c = 0; c < cmax; ++c) {
                const int o = (c << 3) + sub8;
                int i0 = b0 + o, i1 = b1 + o, i2 = b2 + o, i3 = b3 + o;
                int s0 = gsrcs[min(seg0 + i0, slast)];
                int s1 = gsrcs[min(seg0 + i1, slast)];
                int s2 = gsrcs[min(seg0 + i2, slast)];
                int s3 = gsrcs[min(seg0 + i3, slast)];
                s0 = (i0 < e0) ? s0 : zrow;
                s1 = (i1 < e1) ? s1 : zrow;
                s2 = (i2 < e2) ? s2 : zrow;
                s3 = (i3 < e3) ? s3 : zrow;
                uint4 v0 = *(const uint4*)(xh + (size_t)s0 * DIM + fb);
                uint4 v1 = *(const uint4*)(xh + (size_t)s1 * DIM + fb);
                uint4 v2 = *(const uint4*)(xh + (size_t)s2 * DIM + fb);
                uint4 v3 = *(const uint4*)(xh + (size_t)s3 * DIM + fb);
                acc8(A0, v0); acc8(A1, v1); acc8(A2, v2); acc8(A3, v3);
            }
        }

        #pragma unroll
        for (int d = 8; d <= 32; d <<= 1) {
            #pragma unroll
            for (int j = 0; j < 8; ++j) {
                A0[j] += __shfl_xor(A0[j], d, 64);
                A1[j] += __shfl_xor(A1[j], d, 64);
                A2[j] += __shfl_xor(A2[j], d, 64);
                A3[j] += __shfl_xor(A3[j], d, 64);
            }
        }

        const int n0 = node0 + nl;
        if (n0 + 0 < N) out[(size_t)(n0 + 0) * DIM + lane] = epilogue64(A0, wv, bb);
        if (n0 + 1 < N) out[(size_t)(n0 + 1) * DIM + lane] = epilogue64(A1, wv, bb);
        if (n0 + 2 < N) out[(size_t)(n0 + 2) * DIM + lane] = epilogue64(A2, wv, bb);
        if (n0 + 3 < N) out[(size_t)(n0 + 3) * DIM + lane] = epilogue64(A3, wv, bb);
    }
}

// ------------------- tier D: atomic scatter fallback -----------------------
__global__ void gcn_scatter_kernel(const float* __restrict__ x,
                                   const int* __restrict__ edge_index,
                                   float* __restrict__ out, int n_edges) {
    int gid = blockIdx.x * blockDim.x + threadIdx.x;
    int e = gid >> 4;
    if (e >= n_edges) return;
    int j = (gid & 15) << 2;
    int src = edge_index[e];
    int dst = edge_index[n_edges + e];
    const float4 v = *(const float4*)(x + (size_t)src * DIM + j);
    float* o = out + (size_t)dst * DIM + j;
    atomicAdd(o + 0, v.x); atomicAdd(o + 1, v.y);
    atomicAdd(o + 2, v.z); atomicAdd(o + 3, v.w);
}

__global__ void gcn_linear_inplace_kernel(float* __restrict__ out,
                                          const float* __restrict__ W,
                                          const float* __restrict__ bias,
                                          int n_nodes) {
    __shared__ float Wt[DIM * DIM];
    __shared__ float rows[4][DIM];
    int tid = threadIdx.x;
    int col = tid & 63;
    int r = tid >> 6;
    for (int i = tid; i < DIM * DIM; i += 256) {
        int c = i >> 6, k = i & 63;
        Wt[k * DIM + c] = W[i];
    }
    int row = blockIdx.x * 4 + r;
    if (row < n_nodes) rows[r][col] = out[(size_t)row * DIM + col];
    __syncthreads();
    if (row < n_nodes) {
        float a = 0.f;
        #pragma unroll
        for (int k = 0; k < DIM; ++k) a += rows[r][k] * Wt[k * DIM + col];
        out[(size_t)row * DIM + col] = a + bias[col];
    }
}

// ===========================================================================
extern "C" void kernel_launch(void* const* d_in, const int* in_sizes, int n_in,
                              void* d_out, int out_size, void* d_ws, size_t ws_size,
                              hipStream_t stream) {
    const float* x          = (const float*)d_in[0];   // [N, 64]
    const float* W          = (const float*)d_in[1];   // [64, 64]
    const float* bias       = (const float*)d_in[2];   // [64]
    const int*   edge_index = (const int*)d_in[3];     // [2, E] (int32)

    const int E = in_sizes[3] / 2;
    const int N = in_sizes[0] / DIM;
    float* out = (float*)d_out;

    const int nb = (N + BN - 1) >> BN_SHIFT;

    auto align256 = [](size_t v) { return (v + 255) & ~(size_t)255; };
    const size_t xb_b   = align256(((size_t)N + 1) * DIM * 2);   // +1 zero row
    const size_t bin_b  = align256((size_t)E * 4);
    const size_t scan_b = align256((size_t)nb * PB * 4);
    const size_t rt_b   = align256((size_t)nb * 4);
    const size_t gb_b   = align256(((size_t)nb + 1) * 4);
    const size_t srcs_b = align256(((size_t)E + 64) * 4);        // overflow path
    const size_t needA = xb_b + bin_b + scan_b + rt_b + gb_b + srcs_b;

    // src must fit in 26 bits for the (src<<6)|dstlo packing
    if (nb <= NB_MAX && N < (1 << 24) && ws_size >= needA) {
        char* p = (char*)d_ws;
        ushort4* xb4 = (ushort4*)p;          p += xb_b;
        int* binned  = (int*)p;              p += bin_b;
        int* scanbuf = (int*)p;              p += scan_b;
        int* rowtot  = (int*)p;              p += rt_b;
        int* gbase   = (int*)p;              p += gb_b;
        int* gsrcs   = (int*)p;

        const int total4 = N * DIM / 4;

        convert_hist_kernel<<<PB, 1024, 0, stream>>>(
            x, edge_index, xb4, scanbuf, E, N, nb, total4);
        rowscan_kernel<<<(nb + 3) / 4, 256, 0, stream>>>(scanbuf, rowtot, nb);
        basescan_kernel<<<1, 512, 0, stream>>>(rowtot, gbase, nb, E);
        scatter_kernel<<<PB, 1024, 0, stream>>>(
            edge_index, scanbuf, gbase, binned, E, nb);
        sort_gather_kernel<<<nb, 256, 0, stream>>>(
            (const unsigned short*)xb4, binned, gbase, gsrcs, W, bias, out, N, E);
    } else {
        hipMemsetAsync(d_out, 0, (size_t)out_size * sizeof(float), stream);
        long long total = (long long)E * 16;
        int grid = (int)((total + 255) / 256);
        gcn_scatter_kernel<<<grid, 256, 0, stream>>>(x, edge_index, out, E);
        int lgrid = (N + 3) / 4;
        gcn_linear_inplace_kernel<<<lgrid, 256, 0, stream>>>(out, W, bias, N);
    }
}

// Round 14
// 199.706 us; speedup vs baseline: 1.0638x; 1.0638x over previous
//
#include <hip/hip_runtime.h>

// GCN layer: segment_sum(x@W^T)[dst] == segment_sum(x)[dst] @ W^T (linearity).
// Round-14: fixed-capacity buckets kill the scan. 3 dispatches (+1 tiny memset).
//   K1 fused_prep : x->bf16 (+zero row N); per-block LDS hist over nb=
//                   ceil(N/64) buckets; ONE global atomicAdd per (block,
//                   bucket) reserves a contiguous run in the bucket's fixed
//                   1536-slot region; LDS-cursor scatter of
//                   binned[p]=(src<<6)|(dst&63). Overflow (count>1536,
//                   ~impossible for uniform input) diverts to ovf list.
//   K2 sort_gather: block per 64-node bucket; seg=[g*1536, g*1536+gcnt[g]];
//                   LDS counting sort (always fits: len<=1536); branchless
//                   quad gather (bf16 dwordx4, zero-row redirect, shfl_xor
//                   reduce, readlane @ W^T epilogue).  [r13: 79 us]
//   K3 fixup      : processes ovf edges (normally 0): out[dst] += x[src]@W^T.
// Tier D fallback (tiny ws / huge N): atomic scatter + LDS linear.

#define DIM 64
#define BN 64             // nodes per bucket
#define BN_SHIFT 6
#define BN_MASK 63
#define NB_MAX 2048       // max buckets in LDS (8 KB)
#define PB 256            // prep blocks
#define CAPE 1536         // fixed bucket capacity (mean 1024, +16 sigma)
#define OVF_MAX 262144    // overflow list capacity (edges)

__device__ __forceinline__ unsigned short f32_to_bf16_rne(float f) {
    unsigned u = __float_as_uint(f);
    unsigned r = u + 0x7FFFu + ((u >> 16) & 1u);
    return (unsigned short)(r >> 16);
}

// ---------------------------------------------------------------------------
// K1: convert + hist + run-reserve + scatter, all in one kernel.
__global__ __launch_bounds__(1024) void fused_prep_kernel(
        const float* __restrict__ x, const int* __restrict__ ei,
        ushort4* __restrict__ xb4, int* __restrict__ gcnt,
        int* __restrict__ binned, int* __restrict__ ovf,
        int* __restrict__ ovfcnt, int E, int N, int nb, int total4) {
    __shared__ int h[NB_MAX];             // hist, then cursors
    const int t = threadIdx.x;
    const int bid = blockIdx.x;

    for (int b = t; b < nb; b += 1024) h[b] = 0;
    __syncthreads();

    // convert x -> bf16 (overlaps with everything; independent data)
    for (int i = bid * 1024 + t; i < total4; i += PB * 1024) {
        float4 v = ((const float4*)x)[i];
        ushort4 o;
        o.x = f32_to_bf16_rne(v.x); o.y = f32_to_bf16_rne(v.y);
        o.z = f32_to_bf16_rne(v.z); o.w = f32_to_bf16_rne(v.w);
        xb4[i] = o;
    }
    if (bid == 0 && t < 16) {             // zero row N (gather pad target)
        ushort4 z; z.x = 0; z.y = 0; z.z = 0; z.w = 0;
        xb4[(size_t)N * 16 + t] = z;
    }

    // local histogram of dst buckets
    for (int e = bid * 1024 + t; e < E; e += PB * 1024)
        atomicAdd(&h[ei[E + e] >> BN_SHIFT], 1);
    __syncthreads();

    // reserve a contiguous run per bucket (one global atomic per non-empty
    // (block,bucket) pair: ~400K total, L2-hot counters)
    for (int b = t; b < nb; b += 1024) {
        int c = h[b];
        int base = 0;
        if (c > 0) base = atomicAdd(&gcnt[b], c);
        h[b] = b * CAPE + base;           // cursor
    }
    __syncthreads();

    // scatter edges into the reserved runs
    for (int e = bid * 1024 + t; e < E; e += PB * 1024) {
        int s = ei[e];
        int d = ei[E + e];
        int b = d >> BN_SHIFT;
        int p = atomicAdd(&h[b], 1);
        if (p < b * CAPE + CAPE) {
            binned[p] = (s << BN_SHIFT) | (d & BN_MASK);
        } else {                          // bucket overflow (~never)
            int q = atomicAdd(ovfcnt, 1);
            if (q < OVF_MAX) { ovf[2 * q] = s; ovf[2 * q + 1] = d; }
        }
    }
}

// ---------------------------------------------------------------------------
// Gather helpers (proven r8-r13).
__device__ __forceinline__ void acc8(float (&a)[8], const uint4& v) {
    a[0] += __uint_as_float(v.x << 16); a[1] += __uint_as_float(v.x & 0xFFFF0000u);
    a[2] += __uint_as_float(v.y << 16); a[3] += __uint_as_float(v.y & 0xFFFF0000u);
    a[4] += __uint_as_float(v.z << 16); a[5] += __uint_as_float(v.z & 0xFFFF0000u);
    a[6] += __uint_as_float(v.w << 16); a[7] += __uint_as_float(v.w & 0xFFFF0000u);
}

__device__ __forceinline__ float epilogue64(const float (&a)[8],
                                            const float (&wv)[DIM], float bb) {
    float r0 = bb, r1 = 0.f, r2 = 0.f, r3 = 0.f;
    #pragma unroll
    for (int k = 0; k < DIM; k += 4) {
        r0 += __int_as_float(__builtin_amdgcn_readlane(
                  __float_as_int(a[(k + 0) & 7]), (k + 0) >> 3)) * wv[k + 0];
        r1 += __int_as_float(__builtin_amdgcn_readlane(
                  __float_as_int(a[(k + 1) & 7]), (k + 1) >> 3)) * wv[k + 1];
        r2 += __int_as_float(__builtin_amdgcn_readlane(
                  __float_as_int(a[(k + 2) & 7]), (k + 2) >> 3)) * wv[k + 2];
        r3 += __int_as_float(__builtin_amdgcn_readlane(
                  __float_as_int(a[(k + 3) & 7]), (k + 3) >> 3)) * wv[k + 3];
    }
    return (r0 + r1) + (r2 + r3);
}

// ---------------------------------------------------------------------------
// K2: block per 64-node bucket. LDS counting sort of its fixed segment, then
// branchless quad gather. Segment always fits LDS (len <= CAPE).
__global__ __launch_bounds__(256) void sort_gather_kernel(
        const unsigned short* __restrict__ xh, const int* __restrict__ binned,
        const int* __restrict__ gcnt, const float* __restrict__ W,
        const float* __restrict__ bias, float* __restrict__ out, int N) {
    __shared__ int cnt[BN];
    __shared__ int basel[BN + 1];
    __shared__ int tmp[BN];
    __shared__ int slds[CAPE];

    const int t = threadIdx.x;
    const int g = blockIdx.x;
    const int lane = t & 63;
    const int wid = t >> 6;
    const int node0 = g << BN_SHIFT;

    float wv[DIM];
    #pragma unroll
    for (int k4 = 0; k4 < DIM / 4; ++k4) {
        float4 tw = *(const float4*)(W + (size_t)lane * DIM + k4 * 4);
        wv[k4 * 4 + 0] = tw.x; wv[k4 * 4 + 1] = tw.y;
        wv[k4 * 4 + 2] = tw.z; wv[k4 * 4 + 3] = tw.w;
    }
    const float bb = bias[lane];

    const int seg0 = g * CAPE;
    int len = gcnt[g];
    if (len > CAPE) len = CAPE;
    const int seg1 = seg0 + len;

    if (t < BN) cnt[t] = 0;
    __syncthreads();

    for (int i = seg0 + t; i < seg1; i += 256)
        atomicAdd(&cnt[binned[i] & BN_MASK], 1);
    __syncthreads();

    int myv = (t < BN) ? cnt[t] : 0;
    if (t < BN) tmp[t] = myv;
    __syncthreads();
    #pragma unroll
    for (int d = 1; d < BN; d <<= 1) {
        int u = (t < BN && t >= d) ? tmp[t - d] : 0;
        __syncthreads();
        if (t < BN) tmp[t] += u;
        __syncthreads();
    }
    if (t < BN) basel[t] = tmp[t] - myv;
    if (t == BN - 1) basel[BN] = tmp[t];
    if (t < BN) cnt[t] = tmp[t] - myv;        // cursors
    __syncthreads();

    for (int i = seg0 + t; i < seg1; i += 256) {
        int v = binned[i];                    // L2-hot re-read (own 6KB window)
        int p = atomicAdd(&cnt[v & BN_MASK], 1);
        slds[p] = v >> BN_SHIFT;
    }
    __syncthreads();

    const int sub8 = lane >> 3;
    const int fb   = (lane & 7) << 3;
    const int zrow = N;
    for (int q = wid; q < (BN >> 2); q += 4) {
        const int nl = q << 2;
        int b0 = basel[nl + 0], e0 = basel[nl + 1];
        int b1 = basel[nl + 1], e1 = basel[nl + 2];
        int b2 = basel[nl + 2], e2 = basel[nl + 3];
        int b3 = basel[nl + 3], e3 = basel[nl + 4];
        int c0 = (e0 - b0 + 7) >> 3, c1 = (e1 - b1 + 7) >> 3;
        int c2 = (e2 - b2 + 7) >> 3, c3 = (e3 - b3 + 7) >> 3;
        int cmax = max(max(c0, c1), max(c2, c3));
        cmax = __builtin_amdgcn_readfirstlane(cmax);

        float A0[8] = {0.f,0.f,0.f,0.f,0.f,0.f,0.f,0.f};
        float A1[8] = {0.f,0.f,0.f,0.f,0.f,0.f,0.f,0.f};
        float A2[8] = {0.f,0.f,0.f,0.f,0.f,0.f,0.f,0.f};
        float A3[8] = {0.f,0.f,0.f,0.f,0.f,0.f,0.f,0.f};

        for (int c = 0; c < cmax; ++c) {
            const int o = (c << 3) + sub8;
            int i0 = b0 + o, i1 = b1 + o, i2 = b2 + o, i3 = b3 + o;
            int s0 = slds[min(i0, CAPE - 1)];
            int s1 = slds[min(i1, CAPE - 1)];
            int s2 = slds[min(i2, CAPE - 1)];
            int s3 = slds[min(i3, CAPE - 1)];
            s0 = (i0 < e0) ? s0 : zrow;
            s1 = (i1 < e1) ? s1 : zrow;
            s2 = (i2 < e2) ? s2 : zrow;
            s3 = (i3 < e3) ? s3 : zrow;
            uint4 v0 = *(const uint4*)(xh + (size_t)s0 * DIM + fb);
            uint4 v1 = *(const uint4*)(xh + (size_t)s1 * DIM + fb);
            uint4 v2 = *(const uint4*)(xh + (size_t)s2 * DIM + fb);
            uint4 v3 = *(const uint4*)(xh + (size_t)s3 * DIM + fb);
            acc8(A0, v0); acc8(A1, v1); acc8(A2, v2); acc8(A3, v3);
        }

        #pragma unroll
        for (int d = 8; d <= 32; d <<= 1) {
            #pragma unroll
            for (int j = 0; j < 8; ++j) {
                A0[j] += __shfl_xor(A0[j], d, 64);
                A1[j] += __shfl_xor(A1[j], d, 64);
                A2[j] += __shfl_xor(A2[j], d, 64);
                A3[j] += __shfl_xor(A3[j], d, 64);
            }
        }

        const int n0 = node0 + nl;
        if (n0 + 0 < N) out[(size_t)(n0 + 0) * DIM + lane] = epilogue64(A0, wv, bb);
        if (n0 + 1 < N) out[(size_t)(n0 + 1) * DIM + lane] = epilogue64(A1, wv, bb);
        if (n0 + 2 < N) out[(size_t)(n0 + 2) * DIM + lane] = epilogue64(A2, wv, bb);
        if (n0 + 3 < N) out[(size_t)(n0 + 3) * DIM + lane] = epilogue64(A3, wv, bb);
    }
}

// ---------------------------------------------------------------------------
// K3: overflow fixup (normally zero work). out[dst] += x_fp32[src] @ W^T.
__global__ __launch_bounds__(256) void fixup_kernel(
        const float* __restrict__ x, const int* __restrict__ ovf,
        const int* __restrict__ ovfcnt, const float* __restrict__ W,
        float* __restrict__ out) {
    int cnt = *ovfcnt;
    if (cnt > OVF_MAX) cnt = OVF_MAX;
    if (cnt == 0) return;
    const int lane = threadIdx.x & 63;
    const int gwave = (blockIdx.x * blockDim.x + threadIdx.x) >> 6;
    const int total_waves = (gridDim.x * blockDim.x) >> 6;

    float wv[DIM];
    #pragma unroll
    for (int k4 = 0; k4 < DIM / 4; ++k4) {
        float4 tw = *(const float4*)(W + (size_t)lane * DIM + k4 * 4);
        wv[k4 * 4 + 0] = tw.x; wv[k4 * 4 + 1] = tw.y;
        wv[k4 * 4 + 2] = tw.z; wv[k4 * 4 + 3] = tw.w;
    }
    for (int i = gwave; i < cnt; i += total_waves) {
        int s = ovf[2 * i];
        int d = ovf[2 * i + 1];
        float v = x[(size_t)s * DIM + lane];
        float r0 = 0.f, r1 = 0.f, r2 = 0.f, r3 = 0.f;
        #pragma unroll
        for (int k = 0; k < DIM; k += 4) {
            r0 += __int_as_float(__builtin_amdgcn_readlane(__float_as_int(v), k + 0)) * wv[k + 0];
            r1 += __int_as_float(__builtin_amdgcn_readlane(__float_as_int(v), k + 1)) * wv[k + 1];
            r2 += __int_as_float(__builtin_amdgcn_readlane(__float_as_int(v), k + 2)) * wv[k + 2];
            r3 += __int_as_float(__builtin_amdgcn_readlane(__float_as_int(v), k + 3)) * wv[k + 3];
        }
        atomicAdd(&out[(size_t)d * DIM + lane], (r0 + r1) + (r2 + r3));
    }
}

// ------------------- tier D: atomic scatter fallback -----------------------
__global__ void gcn_scatter_kernel(const float* __restrict__ x,
                                   const int* __restrict__ edge_index,
                                   float* __restrict__ out, int n_edges) {
    int gid = blockIdx.x * blockDim.x + threadIdx.x;
    int e = gid >> 4;
    if (e >= n_edges) return;
    int j = (gid & 15) << 2;
    int src = edge_index[e];
    int dst = edge_index[n_edges + e];
    const float4 v = *(const float4*)(x + (size_t)src * DIM + j);
    float* o = out + (size_t)dst * DIM + j;
    atomicAdd(o + 0, v.x); atomicAdd(o + 1, v.y);
    atomicAdd(o + 2, v.z); atomicAdd(o + 3, v.w);
}

__global__ void gcn_linear_inplace_kernel(float* __restrict__ out,
                                          const float* __restrict__ W,
                                          const float* __restrict__ bias,
                                          int n_nodes) {
    __shared__ float Wt[DIM * DIM];
    __shared__ float rows[4][DIM];
    int tid = threadIdx.x;
    int col = tid & 63;
    int r = tid >> 6;
    for (int i = tid; i < DIM * DIM; i += 256) {
        int c = i >> 6, k = i & 63;
        Wt[k * DIM + c] = W[i];
    }
    int row = blockIdx.x * 4 + r;
    if (row < n_nodes) rows[r][col] = out[(size_t)row * DIM + col];
    __syncthreads();
    if (row < n_nodes) {
        float a = 0.f;
        #pragma unroll
        for (int k = 0; k < DIM; ++k) a += rows[r][k] * Wt[k * DIM + col];
        out[(size_t)row * DIM + col] = a + bias[col];
    }
}

// ===========================================================================
extern "C" void kernel_launch(void* const* d_in, const int* in_sizes, int n_in,
                              void* d_out, int out_size, void* d_ws, size_t ws_size,
                              hipStream_t stream) {
    const float* x          = (const float*)d_in[0];   // [N, 64]
    const float* W          = (const float*)d_in[1];   // [64, 64]
    const float* bias       = (const float*)d_in[2];   // [64]
    const int*   edge_index = (const int*)d_in[3];     // [2, E] (int32)

    const int E = in_sizes[3] / 2;
    const int N = in_sizes[0] / DIM;
    float* out = (float*)d_out;

    const int nb = (N + BN - 1) >> BN_SHIFT;

    auto align256 = [](size_t v) { return (v + 255) & ~(size_t)255; };
    const size_t xb_b   = align256(((size_t)N + 1) * DIM * 2);   // +1 zero row
    const size_t bin_b  = align256((size_t)nb * CAPE * 4);
    const size_t cnt_b  = align256(((size_t)nb + 64) * 4);       // gcnt + ovfcnt
    const size_t ovf_b  = align256((size_t)OVF_MAX * 2 * 4);
    const size_t needA = xb_b + bin_b + cnt_b + ovf_b;

    // src must fit in 26 bits for the (src<<6)|dstlo packing
    if (nb <= NB_MAX && N < (1 << 24) && ws_size >= needA) {
        char* p = (char*)d_ws;
        ushort4* xb4 = (ushort4*)p;          p += xb_b;
        int* binned  = (int*)p;              p += bin_b;
        int* gcnt    = (int*)p;              p += cnt_b;
        int* ovf     = (int*)p;
        int* ovfcnt  = gcnt + nb;            // adjacent -> one memset

        const int total4 = N * DIM / 4;

        hipMemsetAsync(gcnt, 0, cnt_b, stream);
        fused_prep_kernel<<<PB, 1024, 0, stream>>>(
            x, edge_index, xb4, gcnt, binned, ovf, ovfcnt, E, N, nb, total4);
        sort_gather_kernel<<<nb, 256, 0, stream>>>(
            (const unsigned short*)xb4, binned, gcnt, W, bias, out, N);
        fixup_kernel<<<64, 256, 0, stream>>>(x, ovf, ovfcnt, W, out);
    } else {
        hipMemsetAsync(d_out, 0, (size_t)out_size * sizeof(float), stream);
        long long total = (long long)E * 16;
        int grid = (int)((total + 255) / 256);
        gcn_scatter_kernel<<<grid, 256, 0, stream>>>(x, edge_index, out, E);
        int lgrid = (N + 3) / 4;
        gcn_linear_inplace_kernel<<<lgrid, 256, 0, stream>>>(out, W, bias, N);
    }
}

// Round 15
// 198.271 us; speedup vs baseline: 1.0715x; 1.0072x over previous
//
#include <hip/hip_runtime.h>

// GCN layer: segment_sum(x@W^T)[dst] == segment_sum(x)[dst] @ W^T (linearity).
// Round-15: 3 dispatches.
//   memset        : gcnt/ovfcnt (6 KB)
//   fused_prep    : REGISTER-CACHED edges (one ei read total): per-thread
//                   <=8 (src,dst) pairs held in regs across phases;
//                   x->bf16 convert; LDS hist; one global atomicAdd per
//                   (block,bucket) run-reserve in fixed 1536-slot regions;
//                   scatter from registers: binned[p]=(src<<6)|(dst&63).
//   sort_gather   : block per 64-node bucket; LDS counting sort of its own
//                   fixed segment; branchless quad gather (bf16 dwordx4,
//                   zero-row redirect, shfl_xor reduce, readlane @ W^T
//                   epilogue); inline overflow fixup (normally 0 work).
// Tier B: r14-style two-pass prep when E too large for the register cache.
// Tier D: atomic scatter + LDS linear (tiny ws / huge N).

#define DIM 64
#define BN 64             // nodes per bucket
#define BN_SHIFT 6
#define BN_MASK 63
#define NB_MAX 2048       // max buckets in LDS (8 KB)
#define PB 256            // prep blocks
#define KMAX 8            // register-cached edges per thread
#define CAPE 1536         // fixed bucket capacity (mean 1024, +16 sigma)
#define OVF_MAX 262144    // overflow list capacity (edges)

__device__ __forceinline__ unsigned short f32_to_bf16_rne(float f) {
    unsigned u = __float_as_uint(f);
    unsigned r = u + 0x7FFFu + ((u >> 16) & 1u);
    return (unsigned short)(r >> 16);
}

// ---------------------------------------------------------------------------
// fused_prep (register-cached): requires E <= PB*1024*KMAX.
__global__ __launch_bounds__(1024) void fused_prep_reg_kernel(
        const float* __restrict__ x, const int* __restrict__ ei,
        ushort4* __restrict__ xb4, int* __restrict__ gcnt,
        int* __restrict__ binned, int* __restrict__ ovf,
        int* __restrict__ ovfcnt, int E, int N, int nb, int total4) {
    __shared__ int h[NB_MAX];             // hist, then cursors
    const int t = threadIdx.x;
    const int bid = blockIdx.x;

    for (int b = t; b < nb; b += 1024) h[b] = 0;
    __syncthreads();

    // load edges ONCE into registers + LDS hist
    int es[KMAX], ds[KMAX];
    #pragma unroll
    for (int k = 0; k < KMAX; ++k) {
        int e = (k * PB + bid) * 1024 + t;      // coalesced per k
        if (e < E) {
            es[k] = ei[e];
            ds[k] = ei[E + e];
            atomicAdd(&h[ds[k] >> BN_SHIFT], 1);
        } else {
            ds[k] = -1;
        }
    }

    // convert x -> bf16 (+ zero row N) — independent, overlaps hist drain
    for (int i = bid * 1024 + t; i < total4; i += PB * 1024) {
        float4 v = ((const float4*)x)[i];
        ushort4 o;
        o.x = f32_to_bf16_rne(v.x); o.y = f32_to_bf16_rne(v.y);
        o.z = f32_to_bf16_rne(v.z); o.w = f32_to_bf16_rne(v.w);
        xb4[i] = o;
    }
    if (bid == 0 && t < 16) {
        ushort4 z; z.x = 0; z.y = 0; z.z = 0; z.w = 0;
        xb4[(size_t)N * 16 + t] = z;
    }
    __syncthreads();

    // reserve a contiguous run per (block,bucket)
    for (int b = t; b < nb; b += 1024) {
        int c = h[b];
        int base = (c > 0) ? atomicAdd(&gcnt[b], c) : 0;
        h[b] = b * CAPE + base;                 // cursor
    }
    __syncthreads();

    // scatter from registers
    #pragma unroll
    for (int k = 0; k < KMAX; ++k) {
        if (ds[k] >= 0) {
            int b = ds[k] >> BN_SHIFT;
            int p = atomicAdd(&h[b], 1);
            if (p < b * CAPE + CAPE) {
                binned[p] = (es[k] << BN_SHIFT) | (ds[k] & BN_MASK);
            } else {
                int q = atomicAdd(ovfcnt, 1);
                if (q < OVF_MAX) { ovf[2 * q] = es[k]; ovf[2 * q + 1] = ds[k]; }
            }
        }
    }
}

// ---------------------------------------------------------------------------
// Tier-B prep (two-pass, r14): for E beyond the register-cache limit.
__global__ __launch_bounds__(1024) void fused_prep_kernel(
        const float* __restrict__ x, const int* __restrict__ ei,
        ushort4* __restrict__ xb4, int* __restrict__ gcnt,
        int* __restrict__ binned, int* __restrict__ ovf,
        int* __restrict__ ovfcnt, int E, int N, int nb, int total4) {
    __shared__ int h[NB_MAX];
    const int t = threadIdx.x;
    const int bid = blockIdx.x;

    for (int b = t; b < nb; b += 1024) h[b] = 0;
    __syncthreads();

    for (int i = bid * 1024 + t; i < total4; i += PB * 1024) {
        float4 v = ((const float4*)x)[i];
        ushort4 o;
        o.x = f32_to_bf16_rne(v.x); o.y = f32_to_bf16_rne(v.y);
        o.z = f32_to_bf16_rne(v.z); o.w = f32_to_bf16_rne(v.w);
        xb4[i] = o;
    }
    if (bid == 0 && t < 16) {
        ushort4 z; z.x = 0; z.y = 0; z.z = 0; z.w = 0;
        xb4[(size_t)N * 16 + t] = z;
    }

    for (int e = bid * 1024 + t; e < E; e += PB * 1024)
        atomicAdd(&h[ei[E + e] >> BN_SHIFT], 1);
    __syncthreads();

    for (int b = t; b < nb; b += 1024) {
        int c = h[b];
        int base = (c > 0) ? atomicAdd(&gcnt[b], c) : 0;
        h[b] = b * CAPE + base;
    }
    __syncthreads();

    for (int e = bid * 1024 + t; e < E; e += PB * 1024) {
        int s = ei[e];
        int d = ei[E + e];
        int b = d >> BN_SHIFT;
        int p = atomicAdd(&h[b], 1);
        if (p < b * CAPE + CAPE) {
            binned[p] = (s << BN_SHIFT) | (d & BN_MASK);
        } else {
            int q = atomicAdd(ovfcnt, 1);
            if (q < OVF_MAX) { ovf[2 * q] = s; ovf[2 * q + 1] = d; }
        }
    }
}

// ---------------------------------------------------------------------------
// Gather helpers (proven r8-r14).
__device__ __forceinline__ void acc8(float (&a)[8], const uint4& v) {
    a[0] += __uint_as_float(v.x << 16); a[1] += __uint_as_float(v.x & 0xFFFF0000u);
    a[2] += __uint_as_float(v.y << 16); a[3] += __uint_as_float(v.y & 0xFFFF0000u);
    a[4] += __uint_as_float(v.z << 16); a[5] += __uint_as_float(v.z & 0xFFFF0000u);
    a[6] += __uint_as_float(v.w << 16); a[7] += __uint_as_float(v.w & 0xFFFF0000u);
}

__device__ __forceinline__ float epilogue64(const float (&a)[8],
                                            const float (&wv)[DIM], float bb) {
    float r0 = bb, r1 = 0.f, r2 = 0.f, r3 = 0.f;
    #pragma unroll
    for (int k = 0; k < DIM; k += 4) {
        r0 += __int_as_float(__builtin_amdgcn_readlane(
                  __float_as_int(a[(k + 0) & 7]), (k + 0) >> 3)) * wv[k + 0];
        r1 += __int_as_float(__builtin_amdgcn_readlane(
                  __float_as_int(a[(k + 1) & 7]), (k + 1) >> 3)) * wv[k + 1];
        r2 += __int_as_float(__builtin_amdgcn_readlane(
                  __float_as_int(a[(k + 2) & 7]), (k + 2) >> 3)) * wv[k + 2];
        r3 += __int_as_float(__builtin_amdgcn_readlane(
                  __float_as_int(a[(k + 3) & 7]), (k + 3) >> 3)) * wv[k + 3];
    }
    return (r0 + r1) + (r2 + r3);
}

// ---------------------------------------------------------------------------
// sort_gather with inline overflow fixup.
__global__ __launch_bounds__(256) void sort_gather_kernel(
        const unsigned short* __restrict__ xh, const float* __restrict__ xf,
        const int* __restrict__ binned, const int* __restrict__ gcnt,
        const int* __restrict__ ovf, const int* __restrict__ ovfcnt,
        const float* __restrict__ W, const float* __restrict__ bias,
        float* __restrict__ out, int N) {
    __shared__ int cnt[BN];
    __shared__ int basel[BN + 1];
    __shared__ int tmp[BN];
    __shared__ int slds[CAPE];

    const int t = threadIdx.x;
    const int g = blockIdx.x;
    const int lane = t & 63;
    const int wid = t >> 6;
    const int node0 = g << BN_SHIFT;

    float wv[DIM];
    #pragma unroll
    for (int k4 = 0; k4 < DIM / 4; ++k4) {
        float4 tw = *(const float4*)(W + (size_t)lane * DIM + k4 * 4);
        wv[k4 * 4 + 0] = tw.x; wv[k4 * 4 + 1] = tw.y;
        wv[k4 * 4 + 2] = tw.z; wv[k4 * 4 + 3] = tw.w;
    }
    const float bb = bias[lane];

    const int seg0 = g * CAPE;
    int len = gcnt[g];
    if (len > CAPE) len = CAPE;
    const int seg1 = seg0 + len;

    if (t < BN) cnt[t] = 0;
    __syncthreads();

    for (int i = seg0 + t; i < seg1; i += 256)
        atomicAdd(&cnt[binned[i] & BN_MASK], 1);
    __syncthreads();

    int myv = (t < BN) ? cnt[t] : 0;
    if (t < BN) tmp[t] = myv;
    __syncthreads();
    #pragma unroll
    for (int d = 1; d < BN; d <<= 1) {
        int u = (t < BN && t >= d) ? tmp[t - d] : 0;
        __syncthreads();
        if (t < BN) tmp[t] += u;
        __syncthreads();
    }
    if (t < BN) basel[t] = tmp[t] - myv;
    if (t == BN - 1) basel[BN] = tmp[t];
    if (t < BN) cnt[t] = tmp[t] - myv;        // cursors
    __syncthreads();

    for (int i = seg0 + t; i < seg1; i += 256) {
        int v = binned[i];                    // L2-hot re-read (own 6KB window)
        int p = atomicAdd(&cnt[v & BN_MASK], 1);
        slds[p] = v >> BN_SHIFT;
    }
    __syncthreads();

    const int sub8 = lane >> 3;
    const int fb   = (lane & 7) << 3;
    const int zrow = N;
    for (int q = wid; q < (BN >> 2); q += 4) {
        const int nl = q << 2;
        int b0 = basel[nl + 0], e0 = basel[nl + 1];
        int b1 = basel[nl + 1], e1 = basel[nl + 2];
        int b2 = basel[nl + 2], e2 = basel[nl + 3];
        int b3 = basel[nl + 3], e3 = basel[nl + 4];
        int c0 = (e0 - b0 + 7) >> 3, c1 = (e1 - b1 + 7) >> 3;
        int c2 = (e2 - b2 + 7) >> 3, c3 = (e3 - b3 + 7) >> 3;
        int cmax = max(max(c0, c1), max(c2, c3));
        cmax = __builtin_amdgcn_readfirstlane(cmax);

        float A0[8] = {0.f,0.f,0.f,0.f,0.f,0.f,0.f,0.f};
        float A1[8] = {0.f,0.f,0.f,0.f,0.f,0.f,0.f,0.f};
        float A2[8] = {0.f,0.f,0.f,0.f,0.f,0.f,0.f,0.f};
        float A3[8] = {0.f,0.f,0.f,0.f,0.f,0.f,0.f,0.f};

        for (int c = 0; c < cmax; ++c) {
            const int o = (c << 3) + sub8;
            int i0 = b0 + o, i1 = b1 + o, i2 = b2 + o, i3 = b3 + o;
            int s0 = slds[min(i0, CAPE - 1)];
            int s1 = slds[min(i1, CAPE - 1)];
            int s2 = slds[min(i2, CAPE - 1)];
            int s3 = slds[min(i3, CAPE - 1)];
            s0 = (i0 < e0) ? s0 : zrow;
            s1 = (i1 < e1) ? s1 : zrow;
            s2 = (i2 < e2) ? s2 : zrow;
            s3 = (i3 < e3) ? s3 : zrow;
            uint4 v0 = *(const uint4*)(xh + (size_t)s0 * DIM + fb);
            uint4 v1 = *(const uint4*)(xh + (size_t)s1 * DIM + fb);
            uint4 v2 = *(const uint4*)(xh + (size_t)s2 * DIM + fb);
            uint4 v3 = *(const uint4*)(xh + (size_t)s3 * DIM + fb);
            acc8(A0, v0); acc8(A1, v1); acc8(A2, v2); acc8(A3, v3);
        }

        #pragma unroll
        for (int d = 8; d <= 32; d <<= 1) {
            #pragma unroll
            for (int j = 0; j < 8; ++j) {
                A0[j] += __shfl_xor(A0[j], d, 64);
                A1[j] += __shfl_xor(A1[j], d, 64);
                A2[j] += __shfl_xor(A2[j], d, 64);
                A3[j] += __shfl_xor(A3[j], d, 64);
            }
        }

        const int n0 = node0 + nl;
        if (n0 + 0 < N) out[(size_t)(n0 + 0) * DIM + lane] = epilogue64(A0, wv, bb);
        if (n0 + 1 < N) out[(size_t)(n0 + 1) * DIM + lane] = epilogue64(A1, wv, bb);
        if (n0 + 2 < N) out[(size_t)(n0 + 2) * DIM + lane] = epilogue64(A2, wv, bb);
        if (n0 + 3 < N) out[(size_t)(n0 + 3) * DIM + lane] = epilogue64(A3, wv, bb);
    }

    // inline overflow fixup: this block handles ovf edges targeting its own
    // bucket (ovfcnt is 0 in practice; cost = one L2 load + branch).
    __syncthreads();
    int oc = *ovfcnt;
    if (oc > 0) {
        if (oc > OVF_MAX) oc = OVF_MAX;
        for (int i = wid; i < oc; i += 4) {
            int s = ovf[2 * i];
            int d = ovf[2 * i + 1];
            if ((d >> BN_SHIFT) == g) {
                float v = xf[(size_t)s * DIM + lane];
                float r = epilogue64(*(const float(*)[8])&v, wv, 0.f);
                // note: epilogue64 expects 8 regs; build acc layout instead:
                // fall back to direct 64-FMA broadcast of v
                float rr0 = 0.f, rr1 = 0.f, rr2 = 0.f, rr3 = 0.f;
                #pragma unroll
                for (int k = 0; k < DIM; k += 4) {
                    rr0 += __int_as_float(__builtin_amdgcn_readlane(__float_as_int(v), k + 0)) * wv[k + 0];
                    rr1 += __int_as_float(__builtin_amdgcn_readlane(__float_as_int(v), k + 1)) * wv[k + 1];
                    rr2 += __int_as_float(__builtin_amdgcn_readlane(__float_as_int(v), k + 2)) * wv[k + 2];
                    rr3 += __int_as_float(__builtin_amdgcn_readlane(__float_as_int(v), k + 3)) * wv[k + 3];
                }
                (void)r;
                atomicAdd(&out[(size_t)d * DIM + lane], (rr0 + rr1) + (rr2 + rr3));
            }
        }
    }
}

// ------------------- tier D: atomic scatter fallback -----------------------
__global__ void gcn_scatter_kernel(const float* __restrict__ x,
                                   const int* __restrict__ edge_index,
                                   float* __restrict__ out, int n_edges) {
    int gid = blockIdx.x * blockDim.x + threadIdx.x;
    int e = gid >> 4;
    if (e >= n_edges) return;
    int j = (gid & 15) << 2;
    int src = edge_index[e];
    int dst = edge_index[n_edges + e];
    const float4 v = *(const float4*)(x + (size_t)src * DIM + j);
    float* o = out + (size_t)dst * DIM + j;
    atomicAdd(o + 0, v.x); atomicAdd(o + 1, v.y);
    atomicAdd(o + 2, v.z); atomicAdd(o + 3, v.w);
}

__global__ void gcn_linear_inplace_kernel(float* __restrict__ out,
                                          const float* __restrict__ W,
                                          const float* __restrict__ bias,
                                          int n_nodes) {
    __shared__ float Wt[DIM * DIM];
    __shared__ float rows[4][DIM];
    int tid = threadIdx.x;
    int col = tid & 63;
    int r = tid >> 6;
    for (int i = tid; i < DIM * DIM; i += 256) {
        int c = i >> 6, k = i & 63;
        Wt[k * DIM + c] = W[i];
    }
    int row = blockIdx.x * 4 + r;
    if (row < n_nodes) rows[r][col] = out[(size_t)row * DIM + col];
    __syncthreads();
    if (row < n_nodes) {
        float a = 0.f;
        #pragma unroll
        for (int k = 0; k < DIM; ++k) a += rows[r][k] * Wt[k * DIM + col];
        out[(size_t)row * DIM + col] = a + bias[col];
    }
}

// ===========================================================================
extern "C" void kernel_launch(void* const* d_in, const int* in_sizes, int n_in,
                              void* d_out, int out_size, void* d_ws, size_t ws_size,
                              hipStream_t stream) {
    const float* x          = (const float*)d_in[0];   // [N, 64]
    const float* W          = (const float*)d_in[1];   // [64, 64]
    const float* bias       = (const float*)d_in[2];   // [64]
    const int*   edge_index = (const int*)d_in[3];     // [2, E] (int32)

    const int E = in_sizes[3] / 2;
    const int N = in_sizes[0] / DIM;
    float* out = (float*)d_out;

    const int nb = (N + BN - 1) >> BN_SHIFT;

    auto align256 = [](size_t v) { return (v + 255) & ~(size_t)255; };
    const size_t xb_b   = align256(((size_t)N + 1) * DIM * 2);   // +1 zero row
    const size_t bin_b  = align256((size_t)nb * CAPE * 4);
    const size_t cnt_b  = align256(((size_t)nb + 64) * 4);       // gcnt + ovfcnt
    const size_t ovf_b  = align256((size_t)OVF_MAX * 2 * 4);
    const size_t needA = xb_b + bin_b + cnt_b + ovf_b;

    // src must fit in 26 bits for the (src<<6)|dstlo packing
    if (nb <= NB_MAX && N < (1 << 24) && ws_size >= needA) {
        char* p = (char*)d_ws;
        ushort4* xb4 = (ushort4*)p;          p += xb_b;
        int* binned  = (int*)p;              p += bin_b;
        int* gcnt    = (int*)p;              p += cnt_b;
        int* ovf     = (int*)p;
        int* ovfcnt  = gcnt + nb;            // adjacent -> one memset

        const int total4 = N * DIM / 4;

        hipMemsetAsync(gcnt, 0, cnt_b, stream);
        if ((long long)E <= (long long)PB * 1024 * KMAX) {
            fused_prep_reg_kernel<<<PB, 1024, 0, stream>>>(
                x, edge_index, xb4, gcnt, binned, ovf, ovfcnt, E, N, nb, total4);
        } else {
            fused_prep_kernel<<<PB, 1024, 0, stream>>>(
                x, edge_index, xb4, gcnt, binned, ovf, ovfcnt, E, N, nb, total4);
        }
        sort_gather_kernel<<<nb, 256, 0, stream>>>(
            (const unsigned short*)xb4, x, binned, gcnt, ovf, ovfcnt,
            W, bias, out, N);
    } else {
        hipMemsetAsync(d_out, 0, (size_t)out_size * sizeof(float), stream);
        long long total = (long long)E * 16;
        int grid = (int)((total + 255) / 256);
        gcn_scatter_kernel<<<grid, 256, 0, stream>>>(x, edge_index, out, E);
        int lgrid = (N + 3) / 4;
        gcn_linear_inplace_kernel<<<lgrid, 256, 0, stream>>>(out, W, bias, N);
    }
}